// Round 2
// baseline (147.197 us; speedup 1.0000x reference)
//
#include <hip/hip_runtime.h>
#include <math.h>

// MultiHeadsGATLayer — algebraic reduction:
//   h = x @ W_heads (only consumed via dot with a_heads halves)
//   => s_src[h][n] = x[n] . (W_heads[h] @ a_src[h]),  s_dst likewise
//   atts[h,e] = lrelu(s_src[h][e0] + s_dst[h][e1]); mt = sum_h atts*lin_w + lin_b
//   dense/mask are sparse: output = colwise softmax, non-edge cells == 0 (exp underflow)
// So: zero the 8192^2 output, build per-column CSR of edges, per-column sparse softmax.
// NOTE: harness delivers integer inputs as int32 (not the reference's int64).

#define ALPHA 0.2f
constexpr int S = 128;
constexpr int O = 64;
constexpr int H = 4;

// --- fold W_heads @ a_heads halves into two 128-vectors per head ---
__global__ void k_wvec(const float* __restrict__ W, const float* __restrict__ a,
                       float* __restrict__ w_src, float* __restrict__ w_dst) {
    int t = blockIdx.x * blockDim.x + threadIdx.x;
    if (t >= H * S) return;
    int h = t / S, s = t % S;
    const float* Wr = W + ((size_t)h * S + s) * O;
    const float* asrc = a + h * 2 * O;
    const float* adst = asrc + O;
    float acc0 = 0.f, acc1 = 0.f;
    for (int o = 0; o < O; ++o) {
        float w = Wr[o];
        acc0 += w * asrc[o];
        acc1 += w * adst[o];
    }
    w_src[h * S + s] = acc0;
    w_dst[h * S + s] = acc1;
}

// --- per-node scalar scores: s_src[h][n] = x[n,:] . w_src[h] ---
__global__ void k_scores(const float* __restrict__ x, const float* __restrict__ w_src,
                         const float* __restrict__ w_dst, float* __restrict__ s_src,
                         float* __restrict__ s_dst, int N) {
    __shared__ float ws[H * S], wd[H * S];
    for (int i = threadIdx.x; i < H * S; i += blockDim.x) {
        ws[i] = w_src[i];
        wd[i] = w_dst[i];
    }
    __syncthreads();
    int n = blockIdx.x * blockDim.x + threadIdx.x;
    if (n >= N) return;
    const float4* xr = (const float4*)(x + (size_t)n * S);
    float accs[H] = {0, 0, 0, 0}, accd[H] = {0, 0, 0, 0};
    for (int i = 0; i < S / 4; ++i) {
        float4 v = xr[i];
        for (int h = 0; h < H; ++h) {
            const float* wsr = ws + h * S + i * 4;
            const float* wdr = wd + h * S + i * 4;
            accs[h] += v.x * wsr[0] + v.y * wsr[1] + v.z * wsr[2] + v.w * wsr[3];
            accd[h] += v.x * wdr[0] + v.y * wdr[1] + v.z * wdr[2] + v.w * wdr[3];
        }
    }
    for (int h = 0; h < H; ++h) {
        s_src[(size_t)h * N + n] = accs[h];
        s_dst[(size_t)h * N + n] = accd[h];
    }
}

// --- histogram of edges per destination column ---
__global__ void k_hist(const int* __restrict__ edges, int* __restrict__ col_count, int N, int E) {
    int e = blockIdx.x * blockDim.x + threadIdx.x;
    if (e >= E) return;
    int c = edges[(size_t)E + e];
    if ((unsigned)c < (unsigned)N) atomicAdd(&col_count[c], 1);
}

// --- exclusive scan of col_count (single block, 256 threads) ---
__global__ void k_scan(const int* __restrict__ cnt, int* __restrict__ start, int N) {
    __shared__ int part[256];
    int t = threadIdx.x;
    int chunk = N / 256;
    int base = t * chunk;
    int s = 0;
    for (int i = 0; i < chunk; ++i) s += cnt[base + i];
    part[t] = s;
    __syncthreads();
    for (int off = 1; off < 256; off <<= 1) {
        int v = (t >= off) ? part[t - off] : 0;
        __syncthreads();
        part[t] += v;
        __syncthreads();
    }
    int excl = (t == 0) ? 0 : part[t - 1];
    for (int i = 0; i < chunk; ++i) {
        start[base + i] = excl;
        excl += cnt[base + i];
    }
    if (t == 255) start[N] = excl;
}

// --- per-edge logit + head combine, scatter into column-sorted CSR arrays ---
__global__ void k_scatter(const int* __restrict__ edges, const float* __restrict__ values,
                          const float* __restrict__ s_src, const float* __restrict__ s_dst,
                          const float* __restrict__ lin_w, const float* __restrict__ lin_b,
                          const int* __restrict__ col_start, int* __restrict__ col_cursor,
                          int* __restrict__ row_sorted, float* __restrict__ val_sorted,
                          float* __restrict__ aval_sorted, int N, int E) {
    int e = blockIdx.x * blockDim.x + threadIdx.x;
    if (e >= E) return;
    int r = edges[e];
    int c = edges[(size_t)E + e];
    if ((unsigned)r >= (unsigned)N || (unsigned)c >= (unsigned)N) return;
    float mt = lin_b[0];
#pragma unroll
    for (int h = 0; h < H; ++h) {
        float att = s_src[(size_t)h * N + r] + s_dst[(size_t)h * N + c];
        att = att >= 0.f ? att : ALPHA * att;
        mt += att * lin_w[h];
    }
    float nv = values[e] * mt;
    int pos = col_start[c] + atomicAdd(&col_cursor[c], 1);
    row_sorted[pos] = r;
    val_sorted[pos] = nv;
    aval_sorted[pos] = values[e];
}

// --- per-column sparse softmax (one wave per column) ---
__global__ void k_softmax(const int* __restrict__ col_start, const int* __restrict__ row_sorted,
                          const float* __restrict__ val_sorted, const float* __restrict__ aval_sorted,
                          float* __restrict__ out, int N) {
    int j = blockIdx.x;
    int beg = col_start[j], end = col_start[j + 1];
    int m = end - beg;
    int lane = threadIdx.x;

    if (m == 0) {
        // empty column: all entries -1e9 -> uniform softmax
        float v = 1.0f / (float)N;
        for (int i = lane; i < N; i += 64) out[(size_t)i * N + j] = v;
        return;
    }

    const int CAP = 1024;
    __shared__ int rws[CAP];
    __shared__ float vls[CAP], avl[CAP], vcb[CAP];

    if (m <= CAP) {
        for (int k = lane; k < m; k += 64) {
            rws[k] = row_sorted[beg + k];
            vls[k] = val_sorted[beg + k];
            avl[k] = aval_sorted[beg + k];
        }
        __syncthreads();
        float lmax = -INFINITY;
        for (int k = lane; k < m; k += 64) {
            int rk = rws[k];
            bool first = true;
            for (int l = 0; l < k; ++l)
                if (rws[l] == rk) { first = false; break; }
            float v = -INFINITY;
            if (first) {
                float dsum = 0.f, asum = 0.f;
                for (int l = 0; l < m; ++l)
                    if (rws[l] == rk) { dsum += vls[l]; asum += avl[l]; }
                float mask = (asum == 1.0f) ? 0.0f : asum;  // a_dense==1 -> 0, else a_dense (dup case)
                v = dsum + mask;
                lmax = fmaxf(lmax, v);
            }
            vcb[k] = v;
        }
#pragma unroll
        for (int off = 32; off; off >>= 1) lmax = fmaxf(lmax, __shfl_xor(lmax, off));
        __syncthreads();
        float lsum = 0.f;
        for (int k = lane; k < m; k += 64) {
            float v = vcb[k];
            if (v != -INFINITY) lsum += expf(v - lmax);
        }
#pragma unroll
        for (int off = 32; off; off >>= 1) lsum += __shfl_xor(lsum, off);
        float inv = 1.0f / lsum;
        for (int k = lane; k < m; k += 64) {
            float v = vcb[k];
            if (v != -INFINITY) out[(size_t)rws[k] * N + j] = expf(v - lmax) * inv;
        }
    } else {
        // fallback: same algorithm straight from global (not expected with E/N ~ 32)
        float lmax = -INFINITY;
        for (int k = lane; k < m; k += 64) {
            int rk = row_sorted[beg + k];
            bool first = true;
            for (int l = 0; l < k; ++l)
                if (row_sorted[beg + l] == rk) { first = false; break; }
            if (first) {
                float dsum = 0.f, asum = 0.f;
                for (int l = 0; l < m; ++l)
                    if (row_sorted[beg + l] == rk) { dsum += val_sorted[beg + l]; asum += aval_sorted[beg + l]; }
                float mask = (asum == 1.0f) ? 0.0f : asum;
                lmax = fmaxf(lmax, dsum + mask);
            }
        }
#pragma unroll
        for (int off = 32; off; off >>= 1) lmax = fmaxf(lmax, __shfl_xor(lmax, off));
        float lsum = 0.f;
        for (int k = lane; k < m; k += 64) {
            int rk = row_sorted[beg + k];
            bool first = true;
            for (int l = 0; l < k; ++l)
                if (row_sorted[beg + l] == rk) { first = false; break; }
            if (first) {
                float dsum = 0.f, asum = 0.f;
                for (int l = 0; l < m; ++l)
                    if (row_sorted[beg + l] == rk) { dsum += val_sorted[beg + l]; asum += aval_sorted[beg + l]; }
                float mask = (asum == 1.0f) ? 0.0f : asum;
                lsum += expf(dsum + mask - lmax);
            }
        }
#pragma unroll
        for (int off = 32; off; off >>= 1) lsum += __shfl_xor(lsum, off);
        float inv = 1.0f / lsum;
        for (int k = lane; k < m; k += 64) {
            int rk = row_sorted[beg + k];
            bool first = true;
            for (int l = 0; l < k; ++l)
                if (row_sorted[beg + l] == rk) { first = false; break; }
            if (first) {
                float dsum = 0.f, asum = 0.f;
                for (int l = 0; l < m; ++l)
                    if (row_sorted[beg + l] == rk) { dsum += val_sorted[beg + l]; asum += aval_sorted[beg + l]; }
                float mask = (asum == 1.0f) ? 0.0f : asum;
                out[(size_t)rk * N + j] = expf(dsum + mask - lmax) * inv;
            }
        }
    }
}

extern "C" void kernel_launch(void* const* d_in, const int* in_sizes, int n_in,
                              void* d_out, int out_size, void* d_ws, size_t ws_size,
                              hipStream_t stream) {
    const float* x = (const float*)d_in[0];
    const int* edges = (const int*)d_in[1];      // harness: integer inputs are int32
    const float* values = (const float*)d_in[2];
    const float* W = (const float*)d_in[3];
    const float* a = (const float*)d_in[4];
    const float* lin_w = (const float*)d_in[5];
    const float* lin_b = (const float*)d_in[6];
    float* out = (float*)d_out;

    const int N = in_sizes[0] / S;   // 8192
    const int E = in_sizes[2];       // 262144

    // workspace layout (256B-aligned slabs)
    char* wsb = (char*)d_ws;
    size_t off = 0;
    auto alloc = [&](size_t bytes) -> void* {
        void* p = wsb + off;
        off += (bytes + 255) & ~(size_t)255;
        return p;
    };
    float* w_src = (float*)alloc((size_t)H * S * 4);
    float* w_dst = (float*)alloc((size_t)H * S * 4);
    float* s_src = (float*)alloc((size_t)H * N * 4);
    float* s_dst = (float*)alloc((size_t)H * N * 4);
    int* col_count = (int*)alloc((size_t)N * 4);
    int* col_start = (int*)alloc((size_t)(N + 1) * 4);
    int* col_cursor = (int*)alloc((size_t)N * 4);
    int* row_sorted = (int*)alloc((size_t)E * 4);
    float* val_sorted = (float*)alloc((size_t)E * 4);
    float* aval_sorted = (float*)alloc((size_t)E * 4);

    hipMemsetAsync(d_out, 0, (size_t)N * N * sizeof(float), stream);
    hipMemsetAsync(col_count, 0, (size_t)N * sizeof(int), stream);
    hipMemsetAsync(col_cursor, 0, (size_t)N * sizeof(int), stream);

    k_wvec<<<(H * S + 255) / 256, 256, 0, stream>>>(W, a, w_src, w_dst);
    k_scores<<<(N + 255) / 256, 256, 0, stream>>>(x, w_src, w_dst, s_src, s_dst, N);
    k_hist<<<(E + 255) / 256, 256, 0, stream>>>(edges, col_count, N, E);
    k_scan<<<1, 256, 0, stream>>>(col_count, col_start, N);
    k_scatter<<<(E + 255) / 256, 256, 0, stream>>>(edges, values, s_src, s_dst, lin_w, lin_b,
                                                   col_start, col_cursor, row_sorted, val_sorted,
                                                   aval_sorted, N, E);
    k_softmax<<<N, 64, 0, stream>>>(col_start, row_sorted, val_sorted, aval_sorted, out, N);
}